// Round 13
// baseline (65.769 us; speedup 1.0000x reference)
//
#include <hip/hip_runtime.h>

#define N_ROWS 262144
#define DIM    64
#define KCB    512

#define MBLOCKS  512
#define MTHREADS 512         // 8 waves; each wave 64 rows = 4 chunks x 16

typedef float f32x4 __attribute__((ext_vector_type(4)));

__device__ inline float dot4(float4 a) {
    return a.x * a.x + a.y * a.y + a.z * a.z + a.w * a.w;
}

// pack 8 f32 (scaled) into 8 fp8-e4m3 bytes via HW cvt_pk
__device__ inline long pk8(float4 f0, float4 f1, float s) {
    int lo = 0, hi = 0;
    lo = __builtin_amdgcn_cvt_pk_fp8_f32(f0.x * s, f0.y * s, lo, false);
    lo = __builtin_amdgcn_cvt_pk_fp8_f32(f0.z * s, f0.w * s, lo, true);
    hi = __builtin_amdgcn_cvt_pk_fp8_f32(f1.x * s, f1.y * s, hi, false);
    hi = __builtin_amdgcn_cvt_pk_fp8_f32(f1.z * s, f1.w * s, hi, true);
    return (long)(((unsigned long)(unsigned)hi << 32) | (unsigned)lo);
}

// pack candidates (score|k) and fold into running min (float-domain monotone)
__device__ inline float packmin(f32x4 acc, unsigned kb, float run) {
    const unsigned mask = 0xFFFFFE00u;
    float p0 = __uint_as_float((__float_as_uint(acc[0]) & mask) | kb);
    float p1 = __uint_as_float((__float_as_uint(acc[1]) & mask) | (kb | 1u));
    float p2 = __uint_as_float((__float_as_uint(acc[2]) & mask) | (kb | 2u));
    float p3 = __uint_as_float((__float_as_uint(acc[3]) & mask) | (kb | 3u));
    return fminf(fminf(fminf(p0, p1), p2), fminf(run, p3));
}

// ---- kernel 0: one-time codebook pre-pack + counter reset ------------------
__global__ void vq_prep(const float* __restrict__ cb, long* __restrict__ cb8,
                        float* __restrict__ wn, unsigned* __restrict__ counter) {
    if (blockIdx.x == 0 && threadIdx.x == 0)
        __hip_atomic_store(counter, 0u, __ATOMIC_RELAXED, __HIP_MEMORY_SCOPE_AGENT);
    const int fg  = blockIdx.x * 512 + threadIdx.x;   // 0..4095
    const int row = fg >> 3, g = fg & 7;
    const float* src = cb + row * DIM + g * 8;
    float4 f0 = *(const float4*)src;
    float4 f1 = *(const float4*)(src + 4);
    float sq = dot4(f0) + dot4(f1);
    sq += __shfl_xor(sq, 1);
    sq += __shfl_xor(sq, 2);
    sq += __shfl_xor(sq, 4);
    const int slot = ((row >> 1) << 4) + ((row & 1) << 3)
                   + (g ^ ((row >> 1) & 7));
    cb8[slot] = pk8(f0, f1, -256.0f);
    if (g == 0) wn[row] = 256.0f + 128.0f * sq;
}

// ---- kernel 1: score + gather-store + fused last-block loss finalize -------
__global__ __launch_bounds__(MTHREADS, 2) void vq_main(
    const float* __restrict__ x, const float* __restrict__ cb,
    const f32x4* __restrict__ img_g, float* __restrict__ out,
    float* __restrict__ partials, unsigned* __restrict__ counter,
    float* __restrict__ out_loss)
{
    __shared__ f32x4 img[2176];            // 34 KiB: cb8[2048] + wn[128]
    __shared__ float red_sh[8];
    __shared__ float fin_sh[MBLOCKS];      // 2 KiB, last-block reduce
    __shared__ unsigned last_flag;

    const int tid    = threadIdx.x;
    const int lane   = tid & 63;
    const int wave   = tid >> 6;           // 0..7
    const int lane15 = lane & 15;
    const int half   = lane >> 4;          // 0..3

    const int wrow = blockIdx.x * 512 + wave * 64;
    const float* xc = x + (size_t)(wrow + lane15) * DIM + half * 8;

    // ---- issue ALL x loads (16 dwordx4, in flight during staging) ----------
    float4 a[4][4];
    #pragma unroll
    for (int c = 0; c < 4; ++c) {
        const float* xp = xc + c * 1024;
        a[c][0] = *(const float4*)xp;        a[c][1] = *(const float4*)(xp + 4);
        a[c][2] = *(const float4*)(xp + 32); a[c][3] = *(const float4*)(xp + 36);
    }

    // ---- stage pre-packed image: pure linear 34 KiB copy -------------------
    #pragma unroll
    for (int it = 0; it < 4; ++it)
        img[tid + it * 512] = img_g[tid + it * 512];
    if (tid < 128) img[2048 + tid] = img_g[2048 + tid];

    // ---- convert all 4 chunks while the barrier drains ---------------------
    float xn[4];
    long  blo[4], bhi[4];
    #pragma unroll
    for (int c = 0; c < 4; ++c) {
        xn[c]  = dot4(a[c][0]) + dot4(a[c][1]) + dot4(a[c][2]) + dot4(a[c][3]);
        blo[c] = pk8(a[c][0], a[c][1], 1.0f);
        bhi[c] = pk8(a[c][2], a[c][3], 1.0f);
    }
    __syncthreads();

    const long*  cb8 = (const long*)img;
    const f32x4* wn4 = img + 2048;

    // per-lane read slots (R8-proven conflict-free)
    const int key  = (lane15 >> 1) & 7;
    const int base = (lane15 >> 1) * 16 + (lane15 & 1) * 8;
    const int slo  = base + (half ^ key);          // dims [8*half, +8)
    const int shi  = slo ^ 4;                      // dims [32+8*half, +8)
    const unsigned hb   = (unsigned)(half * 4);
    const unsigned mask = 0xFFFFFE00u;

    float run0 = __uint_as_float(0x7F7FFFFFu);
    float run1 = run0, run2 = run0, run3 = run0;

    // ---- ONE score loop: each LDS read feeds 4 chunk-MFMA chains -----------
    #pragma unroll 4
    for (int t = 0; t < 32; ++t) {
        long  alo = cb8[t * 128 + slo];
        long  ahi = cb8[t * 128 + shi];
        f32x4 wnv = wn4[t * 4 + half];
        const unsigned kb = (unsigned)(t * 16) | hb;

        f32x4 c0 = wnv;    // acc = 256*(1+0.5||w||^2 - x.w) = 256*score > 0
        c0 = __builtin_amdgcn_mfma_f32_16x16x32_fp8_fp8(alo, blo[0], c0, 0, 0, 0);
        c0 = __builtin_amdgcn_mfma_f32_16x16x32_fp8_fp8(ahi, bhi[0], c0, 0, 0, 0);
        run0 = packmin(c0, kb, run0);

        f32x4 c1 = wnv;
        c1 = __builtin_amdgcn_mfma_f32_16x16x32_fp8_fp8(alo, blo[1], c1, 0, 0, 0);
        c1 = __builtin_amdgcn_mfma_f32_16x16x32_fp8_fp8(ahi, bhi[1], c1, 0, 0, 0);
        run1 = packmin(c1, kb, run1);

        f32x4 c2 = wnv;
        c2 = __builtin_amdgcn_mfma_f32_16x16x32_fp8_fp8(alo, blo[2], c2, 0, 0, 0);
        c2 = __builtin_amdgcn_mfma_f32_16x16x32_fp8_fp8(ahi, bhi[2], c2, 0, 0, 0);
        run2 = packmin(c2, kb, run2);

        f32x4 c3 = wnv;
        c3 = __builtin_amdgcn_mfma_f32_16x16x32_fp8_fp8(alo, blo[3], c3, 0, 0, 0);
        c3 = __builtin_amdgcn_mfma_f32_16x16x32_fp8_fp8(ahi, bhi[3], c3, 0, 0, 0);
        run3 = packmin(c3, kb, run3);
    }

    // ---- per-chunk: cross-half reduce, loss, coalesced gather+store --------
    float runs[4] = {run0, run1, run2, run3};
    float lossAcc = 0.f;
    #pragma unroll
    for (int c = 0; c < 4; ++c) {
        float r = runs[c];
        r = fminf(r, __shfl_xor(r, 16));
        r = fminf(r, __shfl_xor(r, 32));
        float xs = xn[c];
        xs += __shfl_xor(xs, 16); xs += __shfl_xor(xs, 32);

        const unsigned f0 = __float_as_uint(r);
        // packed score = 256*(1+0.5||q||^2-x.q); ||x-q||^2 = xs + pf/128 - 2
        // 4 dup lanes x 0.25 -> wave sum = sum_rows ||x-q||^2 (proven)
        float pf = __uint_as_float(f0 & mask);
        lossAcc += 0.25f * (xs + pf * (1.0f / 128.0f) - 2.0f);
        const int bk0 = (int)(f0 & 511u);

        float* outw = out + (size_t)(wrow + c * 16) * DIM;
        #pragma unroll
        for (int j = 0; j < 4; ++j) {
            const int srcl = (j * 4 + half) & 15;
            int bk = __shfl(bk0, srcl);
            f32x4 qv = *(const f32x4*)(cb + (size_t)bk * DIM + lane15 * 4);
            __builtin_nontemporal_store(qv, (f32x4*)(outw + j * 256 + lane * 4));
        }
    }

    // ---- loss partial + fused finalize (last block, deterministic tree) ----
    #pragma unroll
    for (int off = 1; off < 64; off <<= 1) lossAcc += __shfl_xor(lossAcc, off);
    if (lane == 0) red_sh[wave] = lossAcc;
    __syncthreads();
    if (tid == 0) {
        float s = 0.f;
        #pragma unroll
        for (int w = 0; w < 8; ++w) s += red_sh[w];
        __hip_atomic_store(&partials[blockIdx.x], s, __ATOMIC_RELEASE,
                           __HIP_MEMORY_SCOPE_AGENT);
        unsigned old = __hip_atomic_fetch_add(counter, 1u, __ATOMIC_ACQ_REL,
                                              __HIP_MEMORY_SCOPE_AGENT);
        last_flag = (old == MBLOCKS - 1) ? 1u : 0u;
    }
    __syncthreads();
    if (last_flag) {
        fin_sh[tid] = __hip_atomic_load(&partials[tid], __ATOMIC_ACQUIRE,
                                        __HIP_MEMORY_SCOPE_AGENT);
        __syncthreads();
        #pragma unroll
        for (int s = MBLOCKS / 2; s > 0; s >>= 1) {
            if (tid < s) fin_sh[tid] += fin_sh[tid + s];
            __syncthreads();
        }
        // partials = sum_rows ||x-q||^2 ; vq_loss = 1.25 * sum / (N*D)
        if (tid == 0) out_loss[0] = fin_sh[0] * (1.25f / (float)(N_ROWS * DIM));
    }
}

extern "C" void kernel_launch(void* const* d_in, const int* in_sizes, int n_in,
                              void* d_out, int out_size, void* d_ws, size_t ws_size,
                              hipStream_t stream) {
    const float* x  = (const float*)d_in[0];
    const float* cb = (const float*)d_in[1];
    float* out      = (float*)d_out;
    long*  ws_cb8   = (long*)d_ws;                          // 4096 longs (32 KiB)
    float* ws_wn    = (float*)((char*)d_ws + 32768);        // 512 floats (2 KiB)
    float* partials = (float*)((char*)d_ws + 36864);        // 512 floats (2 KiB)
    unsigned* counter = (unsigned*)((char*)d_ws + 40960);   // 1 u32

    hipLaunchKernelGGL(vq_prep, dim3(8), dim3(512), 0, stream,
                       cb, ws_cb8, ws_wn, counter);
    hipLaunchKernelGGL(vq_main, dim3(MBLOCKS), dim3(MTHREADS), 0, stream,
                       x, cb, (const f32x4*)d_ws, out, partials, counter,
                       out + (size_t)N_ROWS * DIM);
}

// Round 14
// 39.148 us; speedup vs baseline: 1.6800x; 1.6800x over previous
//
#include <hip/hip_runtime.h>

#define N_ROWS 262144
#define DIM    64
#define KCB    512

#define MBLOCKS  512
#define MTHREADS 512         // 8 waves; each wave 64 rows = 2 groups x 2 chunks x 16

typedef float f32x4 __attribute__((ext_vector_type(4)));

__device__ inline float dot4(float4 a) {
    return a.x * a.x + a.y * a.y + a.z * a.z + a.w * a.w;
}

// pack 8 f32 (scaled) into 8 fp8-e4m3 bytes via HW cvt_pk
__device__ inline long pk8(float4 f0, float4 f1, float s) {
    int lo = 0, hi = 0;
    lo = __builtin_amdgcn_cvt_pk_fp8_f32(f0.x * s, f0.y * s, lo, false);
    lo = __builtin_amdgcn_cvt_pk_fp8_f32(f0.z * s, f0.w * s, lo, true);
    hi = __builtin_amdgcn_cvt_pk_fp8_f32(f1.x * s, f1.y * s, hi, false);
    hi = __builtin_amdgcn_cvt_pk_fp8_f32(f1.z * s, f1.w * s, hi, true);
    return (long)(((unsigned long)(unsigned)hi << 32) | (unsigned)lo);
}

// pack candidates (score|k) and fold into running min (float-domain monotone)
__device__ inline float packmin(f32x4 acc, unsigned kb, float run) {
    const unsigned mask = 0xFFFFFE00u;
    float p0 = __uint_as_float((__float_as_uint(acc[0]) & mask) | kb);
    float p1 = __uint_as_float((__float_as_uint(acc[1]) & mask) | (kb | 1u));
    float p2 = __uint_as_float((__float_as_uint(acc[2]) & mask) | (kb | 2u));
    float p3 = __uint_as_float((__float_as_uint(acc[3]) & mask) | (kb | 3u));
    return fminf(fminf(fminf(p0, p1), p2), fminf(run, p3));
}

// ---- kernel 0: one-time codebook pre-pack into the exact LDS image ---------
__global__ void vq_prep(const float* __restrict__ cb, long* __restrict__ cb8,
                        float* __restrict__ wn) {
    const int fg  = blockIdx.x * 512 + threadIdx.x;   // 0..4095
    const int row = fg >> 3, g = fg & 7;
    const float* src = cb + row * DIM + g * 8;
    float4 f0 = *(const float4*)src;
    float4 f1 = *(const float4*)(src + 4);
    float sq = dot4(f0) + dot4(f1);
    sq += __shfl_xor(sq, 1);
    sq += __shfl_xor(sq, 2);
    sq += __shfl_xor(sq, 4);
    const int slot = ((row >> 1) << 4) + ((row & 1) << 3)
                   + (g ^ ((row >> 1) & 7));
    cb8[slot] = pk8(f0, f1, -256.0f);
    if (g == 0) wn[row] = 256.0f + 128.0f * sq;
}

// score 512 codewords for two 16-row chunks sharing every LDS read
#define SCORE2(RUNA, RUNB, BLOA, BHIA, BLOB, BHIB)                            \
    _Pragma("unroll 8")                                                       \
    for (int t = 0; t < 32; ++t) {                                            \
        long  alo_ = cb8[t * 128 + slo];                                      \
        long  ahi_ = cb8[t * 128 + shi];                                      \
        f32x4 wnv_ = wn4[t * 4 + half];                                       \
        const unsigned kb_ = (unsigned)(t * 16) | hb;                         \
        f32x4 ca_ = wnv_;                                                     \
        ca_ = __builtin_amdgcn_mfma_f32_16x16x32_fp8_fp8(alo_, BLOA, ca_, 0, 0, 0); \
        ca_ = __builtin_amdgcn_mfma_f32_16x16x32_fp8_fp8(ahi_, BHIA, ca_, 0, 0, 0); \
        RUNA = packmin(ca_, kb_, RUNA);                                       \
        f32x4 cz_ = wnv_;                                                     \
        cz_ = __builtin_amdgcn_mfma_f32_16x16x32_fp8_fp8(alo_, BLOB, cz_, 0, 0, 0); \
        cz_ = __builtin_amdgcn_mfma_f32_16x16x32_fp8_fp8(ahi_, BHIB, cz_, 0, 0, 0); \
        RUNB = packmin(cz_, kb_, RUNB);                                       \
    }

// per-chunk epilogue: cross-half reduce, loss, coalesced gather+store
#define EPI(RUN, XN, ROWOFF)                                                  \
    {                                                                         \
        float r_ = fminf(RUN, __shfl_xor(RUN, 16));                           \
        r_ = fminf(r_, __shfl_xor(r_, 32));                                   \
        float xs_ = XN;                                                       \
        xs_ += __shfl_xor(xs_, 16); xs_ += __shfl_xor(xs_, 32);               \
        const unsigned f_ = __float_as_uint(r_);                              \
        float pf_ = __uint_as_float(f_ & 0xFFFFFE00u);                        \
        lossAcc += 0.25f * (xs_ + pf_ * (1.0f / 128.0f) - 2.0f);              \
        const int bk_ = (int)(f_ & 511u);                                     \
        float* outw_ = out + (size_t)(wrow + ROWOFF) * DIM;                   \
        _Pragma("unroll")                                                     \
        for (int j = 0; j < 4; ++j) {                                         \
            const int srcl_ = (j * 4 + half) & 15;                           \
            int bkj_ = __shfl(bk_, srcl_);                                    \
            f32x4 qv_ = *(const f32x4*)(cb + (size_t)bkj_ * DIM + lane15 * 4);\
            *(f32x4*)(outw_ + j * 256 + lane * 4) = qv_;                      \
        }                                                                     \
    }

// ---- kernel 1: two-group pipeline with asm-pinned prefetch -----------------
__global__ __launch_bounds__(MTHREADS, 2) void vq_main(
    const float* __restrict__ x, const float* __restrict__ cb,
    const f32x4* __restrict__ img_g, float* __restrict__ out,
    float* __restrict__ partials)
{
    __shared__ f32x4 img[2176];            // 34 KiB: cb8[2048] + wn[128]
    __shared__ float red_sh[8];

    const int tid    = threadIdx.x;
    const int lane   = tid & 63;
    const int wave   = tid >> 6;           // 0..7
    const int lane15 = lane & 15;
    const int half   = lane >> 4;          // 0..3

    const int wrow = blockIdx.x * 512 + wave * 64;
    const float* xc = x + (size_t)(wrow + lane15) * DIM + half * 8;

    // ---- issue group0 (chunks 0,1) loads; PIN above staging ----------------
    float4 r00, r01, r02, r03, r10, r11, r12, r13;
    r00 = *(const float4*)xc;          r01 = *(const float4*)(xc + 4);
    r02 = *(const float4*)(xc + 32);   r03 = *(const float4*)(xc + 36);
    r10 = *(const float4*)(xc + 1024); r11 = *(const float4*)(xc + 1028);
    r12 = *(const float4*)(xc + 1056); r13 = *(const float4*)(xc + 1060);
    asm volatile("" ::: "memory");     // loads may not sink below this point

    // ---- stage pre-packed image: pure linear 34 KiB copy -------------------
    #pragma unroll
    for (int it = 0; it < 4; ++it)
        img[tid + it * 512] = img_g[tid + it * 512];
    if (tid < 128) img[2048 + tid] = img_g[2048 + tid];

    // ---- convert group0 while the barrier drains ---------------------------
    float xnA = dot4(r00) + dot4(r01) + dot4(r02) + dot4(r03);
    float xnB = dot4(r10) + dot4(r11) + dot4(r12) + dot4(r13);
    long bloA = pk8(r00, r01, 1.0f), bhiA = pk8(r02, r03, 1.0f);
    long bloB = pk8(r10, r11, 1.0f), bhiB = pk8(r12, r13, 1.0f);
    __syncthreads();

    const long*  cb8 = (const long*)img;
    const f32x4* wn4 = img + 2048;

    // per-lane read slots (R8-proven conflict-free)
    const int key  = (lane15 >> 1) & 7;
    const int base = (lane15 >> 1) * 16 + (lane15 & 1) * 8;
    const int slo  = base + (half ^ key);          // dims [8*half, +8)
    const int shi  = slo ^ 4;                      // dims [32+8*half, +8)
    const unsigned hb = (unsigned)(half * 4);
    float lossAcc = 0.f;

    // ---- G0: issue group1 loads (PINNED), score chunks 0&1, store ----------
    r00 = *(const float4*)(xc + 2048); r01 = *(const float4*)(xc + 2052);
    r02 = *(const float4*)(xc + 2080); r03 = *(const float4*)(xc + 2084);
    r10 = *(const float4*)(xc + 3072); r11 = *(const float4*)(xc + 3076);
    r12 = *(const float4*)(xc + 3104); r13 = *(const float4*)(xc + 3108);
    asm volatile("" ::: "memory");     // in flight during the score loop below

    {
        float runA = __uint_as_float(0x7F7FFFFFu), runB = runA;
        SCORE2(runA, runB, bloA, bhiA, bloB, bhiB);
        EPI(runA, xnA, 0);
        EPI(runB, xnB, 16);
    }

    // ---- convert group1 (loads drained by use) -----------------------------
    xnA = dot4(r00) + dot4(r01) + dot4(r02) + dot4(r03);
    xnB = dot4(r10) + dot4(r11) + dot4(r12) + dot4(r13);
    bloA = pk8(r00, r01, 1.0f); bhiA = pk8(r02, r03, 1.0f);
    bloB = pk8(r10, r11, 1.0f); bhiB = pk8(r12, r13, 1.0f);

    // ---- G1: score chunks 2&3, store ---------------------------------------
    {
        float runA = __uint_as_float(0x7F7FFFFFu), runB = runA;
        SCORE2(runA, runB, bloA, bhiA, bloB, bhiB);
        EPI(runA, xnA, 32);
        EPI(runB, xnB, 48);
    }

    // ---- loss partial ------------------------------------------------------
    #pragma unroll
    for (int off = 1; off < 64; off <<= 1) lossAcc += __shfl_xor(lossAcc, off);
    if (lane == 0) red_sh[wave] = lossAcc;
    __syncthreads();
    if (tid == 0) {
        float s = 0.f;
        #pragma unroll
        for (int w = 0; w < 8; ++w) s += red_sh[w];
        partials[blockIdx.x] = s;
    }
}

// ---- kernel 2: final loss reduction (512 partials) -------------------------
__global__ void vq_finalize(const float* __restrict__ partials,
                            float* __restrict__ out_loss) {
    __shared__ float sh[256];
    int t = threadIdx.x;
    sh[t] = partials[t] + partials[t + 256];
    __syncthreads();
    #pragma unroll
    for (int s = 128; s > 0; s >>= 1) {
        if (t < s) sh[t] += sh[t + s];
        __syncthreads();
    }
    // partials = sum_rows ||x-q||^2 ; vq_loss = 1.25 * sum / (N*D)
    if (t == 0) out_loss[0] = sh[0] * (1.25f / (float)(N_ROWS * DIM));
}

extern "C" void kernel_launch(void* const* d_in, const int* in_sizes, int n_in,
                              void* d_out, int out_size, void* d_ws, size_t ws_size,
                              hipStream_t stream) {
    const float* x  = (const float*)d_in[0];
    const float* cb = (const float*)d_in[1];
    float* out      = (float*)d_out;
    long*  ws_cb8   = (long*)d_ws;                          // 4096 longs (32 KiB)
    float* ws_wn    = (float*)((char*)d_ws + 32768);        // 512 floats (2 KiB)
    float* partials = (float*)((char*)d_ws + 36864);        // 512 floats

    hipLaunchKernelGGL(vq_prep, dim3(8), dim3(512), 0, stream, cb, ws_cb8, ws_wn);
    hipLaunchKernelGGL(vq_main, dim3(MBLOCKS), dim3(MTHREADS), 0, stream,
                       x, cb, (const f32x4*)d_ws, out, partials);
    hipLaunchKernelGGL(vq_finalize, dim3(1), dim3(256), 0, stream,
                       partials, out + (size_t)N_ROWS * DIM);
}